// Round 1
// baseline (550.117 us; speedup 1.0000x reference)
//
#include <hip/hip_runtime.h>

#define BB 16
#define NN 2048
#define MM 2048
#define EPSF 1e-9f
#define SKIPT (-135.0f)   // exp2(arg) == 0 below this

typedef float v2f __attribute__((ext_vector_type(2)));

constexpr int CH = 64;     // stream chunk length (2 outputs/thread)
constexpr int NCHUNK = 32; // NN/CH == MM/CH
// grid: BB batches x 4 groups(512 own-points) x 32 chunks = 2048 blocks
// Accumulation scheme: NO global atomics. Each streaming kernel writes its
// per-chunk partial sums with coalesced plain stores into X_part[chunk][*];
// the consumer kernel's prelude reduces the 32 partials. Partials are fully
// overwritten every kernel -> no ping-pong parity, no zeroing needed.

// ---------------- init ----------------
__global__ __launch_bounds__(256) void init_kernel(
    const float* __restrict__ xyz1, const float* __restrict__ xyz2,
    float4* __restrict__ P1, float4* __restrict__ P2,
    float* __restrict__ remR0, float* __restrict__ out)
{
    const int t = blockIdx.x * 256 + threadIdx.x;   // 0 .. BB*NN-1
    if (t < BB * NN)
        P1[t] = make_float4(xyz1[3*t+0], xyz1[3*t+1], xyz1[3*t+2], 0.0f);
    if (t < BB * MM) {
        P2[t] = make_float4(xyz2[3*t+0], xyz2[3*t+1], xyz2[3*t+2], 0.0f);
        remR0[t] = 1.0f;
    }
    if (t < BB) out[t] = 0.0f;
}

// ---------------- rowInit: RS_part[ic][row] = sum_{l in chunk ic} exp(coef0*d2) ----------------
__global__ __launch_bounds__(256) void rowInit(
    const float4* __restrict__ P1, const float4* __restrict__ P2,
    float* __restrict__ RSp, float coef)
{
    __shared__ float4 sCol[CH];
    const int chunks = MM / CH;                   // 32
    const int bpb = (NN / 512) * chunks;          // 128
    const int batch = blockIdx.x / bpb;
    const int rem   = blockIdx.x % bpb;
    const int rg    = rem / chunks;
    const int ic    = rem % chunks;
    const int t     = threadIdx.x;

    if (t < CH) sCol[t] = P2[batch * MM + ic * CH + t];
    __syncthreads();

    const int row0 = batch * NN + rg * 512 + t;
    const int row1 = row0 + 256;
    const float4 p0 = P1[row0];
    const float4 p1 = P1[row1];
    const v2f px = {p0.x, p1.x}, py = {p0.y, p1.y}, pz = {p0.z, p1.z};
    v2f rs = {0.0f, 0.0f};
#pragma unroll 4
    for (int ii = 0; ii < CH; ++ii) {
        const float4 q = sCol[ii];
        const v2f dx = px - q.x, dy = py - q.y, dz = pz - q.z;
        const v2f g = coef * (dx*dx + dy*dy + dz*dz);
        if (__ballot((g.x > SKIPT) || (g.y > SKIPT))) {
            v2f e;
            e.x = __builtin_amdgcn_exp2f(g.x);
            e.y = __builtin_amdgcn_exp2f(g.y);
            rs += e;
        }
    }
    float* dst = RSp + ic * (BB * NN);
    dst[row0] = rs.x;           // coalesced plain store, no atomic
    dst[row1] = rs.y;
}

// ---------------- colK: row-finalize prelude (with 32-partial reduction) + column-partial stream ----------------
// MODE 0: j==0 (remL=1, no U read). MODE 1: general. MODE 2: j==9 (coef==0 -> e=scale).
template<int MODE, bool SPARSE>
__global__ __launch_bounds__(256) void colK(
    const float4* __restrict__ P1, const float4* __restrict__ P2,
    const float* __restrict__ RSp, const float* __restrict__ Up,
    const float* __restrict__ remLr, float* __restrict__ remLw,
    const float* __restrict__ scaler, float* __restrict__ scalew,
    float* __restrict__ Sp, float* __restrict__ Tp,
    float coef)
{
    __shared__ float4 sRow[CH];                   // x1,y1,z1,scale_j
    __shared__ float redA[256], redB[256];
    const int chunks = NN / CH;                   // 32
    const int bpb = (MM / 512) * chunks;          // 128
    const int batch = blockIdx.x / bpb;
    const int rem   = blockIdx.x % bpb;
    const int cg    = rem / chunks;
    const int ic    = rem % chunks;
    const int t     = threadIdx.x;

    // prelude A: parallel 32-chunk partial reduction (all 256 threads, coalesced)
    {
        const int r = t & 63, g4 = t >> 6;        // wave g4 handles chunks g4*8..g4*8+7
        const int gi = batch * NN + ic * CH + r;
        float aRS = 0.0f, aU = 0.0f;
#pragma unroll
        for (int k = 0; k < 8; ++k) {
            const int c = g4 * 8 + k;
            aRS += RSp[c * (BB*NN) + gi];
            if (MODE != 0) aU += Up[c * (BB*NN) + gi];
        }
        redA[t] = aRS;
        redB[t] = aU;
    }
    __syncthreads();
    // prelude B: finalize rows of this chunk (duplicated by 4 cg-blocks; identical values)
    if (t < CH) {
        const int gi = batch * NN + ic * CH + t;
        const float rsum = redA[t] + redA[t+64] + redA[t+128] + redA[t+192];
        float L;
        if (MODE == 0) L = 1.0f;
        else {
            const float usum = redB[t] + redB[t+64] + redB[t+128] + redB[t+192];
            L = fmaxf(remLr[gi] - scaler[gi] * usum, 0.0f);
        }
        remLw[gi] = L;
        const float sc = L / (rsum + EPSF);
        scalew[gi] = sc;
        const float4 p = P1[gi];
        sRow[t] = make_float4(p.x, p.y, p.z, sc);
    }
    __syncthreads();

    const int col0 = batch * MM + cg * 512 + t;
    const int col1 = col0 + 256;
    const float4 q0 = P2[col0];
    const float4 q1 = P2[col1];
    const v2f qx = {q0.x, q1.x}, qy = {q0.y, q1.y}, qz = {q0.z, q1.z};
    v2f s = {0.0f, 0.0f}, tt = {0.0f, 0.0f};
#pragma unroll 4
    for (int ii = 0; ii < CH; ++ii) {
        const float4 a = sRow[ii];
        const v2f dx = a.x - qx, dy = a.y - qy, dz = a.z - qz;
        const v2f d2 = dx*dx + dy*dy + dz*dz;
        if (SPARSE) {
            const v2f g = coef * d2;
            if (__ballot((g.x > SKIPT) || (g.y > SKIPT))) {
                v2f e;
                e.x = __builtin_amdgcn_exp2f(g.x);
                e.y = __builtin_amdgcn_exp2f(g.y);
                e *= a.w;
                v2f sq;
                sq.x = __builtin_amdgcn_sqrtf(d2.x);
                sq.y = __builtin_amdgcn_sqrtf(d2.y);
                s += e;
                tt += e * sq;
            }
        } else {
            v2f e;
            if (MODE == 2) { e.x = a.w; e.y = a.w; }
            else {
                const v2f g = coef * d2;
                e.x = a.w * __builtin_amdgcn_exp2f(g.x);
                e.y = a.w * __builtin_amdgcn_exp2f(g.y);
            }
            v2f sq;
            sq.x = __builtin_amdgcn_sqrtf(d2.x);
            sq.y = __builtin_amdgcn_sqrtf(d2.y);
            s += e;
            tt += e * sq;
        }
    }
    float* dS = Sp + ic * (BB*MM);
    float* dT = Tp + ic * (BB*MM);
    dS[col0] = s.x;  dT[col0] = tt.x;             // coalesced plain stores
    dS[col1] = s.y;  dT[col1] = tt.y;
}

// ---------------- rowK: col-finalize prelude (with 32-partial reduction) + row-partial stream ----------------
// MODE 1: general. MODE 2: j==8 (rs = sum remR_9, u at coefP direct).
template<int MODE, bool SPARSE>
__global__ __launch_bounds__(256) void rowK(
    const float4* __restrict__ P1, const float4* __restrict__ P2,
    const float* __restrict__ Sp, const float* __restrict__ Tp,
    const float* __restrict__ remRr, float* __restrict__ remRw,
    float* __restrict__ RSp, float* __restrict__ Up,
    float* __restrict__ out,
    float coefP, float coefN)
{
    __shared__ float4 sCol[CH];                   // x2,y2,z2,remR_{j+1}
    __shared__ float  sPc[CH];                    // Pcol_j
    __shared__ float  redA[256], redB[256];
    const int chunks = MM / CH;                   // 32
    const int bpb = (NN / 512) * chunks;          // 128
    const int batch = blockIdx.x / bpb;
    const int rem   = blockIdx.x % bpb;
    const int rg    = rem / chunks;
    const int ic    = rem % chunks;
    const int t     = threadIdx.x;

    // prelude A: parallel 32-chunk partial reduction of S,T (all 256 threads)
    {
        const int r = t & 63, g4 = t >> 6;
        const int gl = batch * MM + ic * CH + r;
        float aS = 0.0f, aT = 0.0f;
#pragma unroll
        for (int k = 0; k < 8; ++k) {
            const int c = g4 * 8 + k;
            aS += Sp[c * (BB*MM) + gl];
            aT += Tp[c * (BB*MM) + gl];
        }
        redA[t] = aS;
        redB[t] = aT;
    }
    __syncthreads();
    // prelude B: finalize cols of this chunk (duplicated by 4 rg-blocks; identical values)
    float cacc = 0.0f;
    if (t < CH) {
        const int gl = batch * MM + ic * CH + t;
        const float s  = redA[t] + redA[t+64] + redA[t+128] + redA[t+192];
        const float t2 = redB[t] + redB[t+64] + redB[t+128] + redB[t+192];
        const float R  = remRr[gl];
        const float sumr = s * R;
        const float cons = fminf(R / (sumr + EPSF), 1.0f);
        const float pcol = R * cons;
        const float Rn   = fmaxf(R - sumr * cons, 0.0f);
        remRw[gl] = Rn;
        const float4 p = P2[gl];
        sCol[t] = make_float4(p.x, p.y, p.z, Rn);
        sPc[t]  = pcol;
        if (rg == 0) cacc = pcol * t2;            // cost contribution (once per chunk)
    }
    if (rg == 0) {
#pragma unroll
        for (int off = 32; off > 0; off >>= 1) cacc += __shfl_xor(cacc, off, 64);
        if (t == 0) atomicAdd(out + batch, cacc);
    }
    __syncthreads();

    const int row0 = batch * NN + rg * 512 + t;
    const int row1 = row0 + 256;
    const float4 p0 = P1[row0];
    const float4 p1 = P1[row1];
    const v2f px = {p0.x, p1.x}, py = {p0.y, p1.y}, pz = {p0.z, p1.z};
    v2f rs = {0.0f, 0.0f}, u = {0.0f, 0.0f};
#pragma unroll 4
    for (int ii = 0; ii < CH; ++ii) {
        const float4 q = sCol[ii];
        const float pc = sPc[ii];
        const v2f dx = px - q.x, dy = py - q.y, dz = pz - q.z;
        const v2f d2 = dx*dx + dy*dy + dz*dz;
        if (MODE == 1) {
            const v2f g = coefN * d2;
            if (SPARSE) {
                if (__ballot((g.x > SKIPT) || (g.y > SKIPT))) {
                    v2f en;
                    en.x = __builtin_amdgcn_exp2f(g.x);
                    en.y = __builtin_amdgcn_exp2f(g.y);
                    const v2f e2 = en * en;
                    const v2f e4 = e2 * e2;
                    u  += e4 * pc;                // e_prev = e_next^4
                    rs += en * q.w;
                }
            } else {
                v2f en;
                en.x = __builtin_amdgcn_exp2f(g.x);
                en.y = __builtin_amdgcn_exp2f(g.y);
                const v2f e2 = en * en;
                const v2f e4 = e2 * e2;
                u  += e4 * pc;
                rs += en * q.w;
            }
        } else {
            const v2f g = coefP * d2;
            v2f ep;
            ep.x = __builtin_amdgcn_exp2f(g.x);
            ep.y = __builtin_amdgcn_exp2f(g.y);
            u  += ep * pc;
            rs += q.w;                            // e_next = exp(0) = 1
        }
    }
    float* dRS = RSp + ic * (BB*NN);
    float* dU  = Up  + ic * (BB*NN);
    dRS[row0] = rs.x;  dU[row0] = u.x;            // coalesced plain stores
    dRS[row1] = rs.y;  dU[row1] = u.y;
}

// ---------------- finCost: cost for level 9 (reduces 32 partials, no state updates) ----------------
__global__ __launch_bounds__(256) void finCost(
    const float* __restrict__ Sp, const float* __restrict__ Tp,
    const float* __restrict__ remRr, float* __restrict__ out)
{
    const int idx = blockIdx.x * 256 + threadIdx.x;
    const int batch = idx / MM;
    float s = 0.0f, t2 = 0.0f;
#pragma unroll 8
    for (int c = 0; c < NCHUNK; ++c) {
        s  += Sp[c * (BB*MM) + idx];
        t2 += Tp[c * (BB*MM) + idx];
    }
    const float R = remRr[idx];
    const float sumr = s * R;
    const float cons = fminf(R / (sumr + EPSF), 1.0f);
    float c = R * cons * t2;
#pragma unroll
    for (int off = 32; off > 0; off >>= 1) c += __shfl_xor(c, off, 64);
    if ((threadIdx.x & 63) == 0) atomicAdd(out + batch, c);
}

extern "C" void kernel_launch(void* const* d_in, const int* in_sizes, int n_in,
                              void* d_out, int out_size, void* d_ws, size_t ws_size,
                              hipStream_t stream)
{
    const float* xyz1 = (const float*)d_in[0];
    const float* xyz2 = (const float*)d_in[1];
    float* out = (float*)d_out;

    const int BN = BB * NN, BM = BB * MM;
    float4* P1 = (float4*)d_ws;
    float4* P2 = P1 + BN;
    float* remL  = (float*)(P2 + BM);       // [2][BN]  ping-pong
    float* scale = remL + 2 * BN;           // [2][BN]  ping-pong
    float* remR  = scale + 2 * BN;          // [2][BM]  ping-pong
    float* RSp   = remR + 2 * BM;           // [NCHUNK][BN] partials (no parity)
    float* Up    = RSp + NCHUNK * BN;       // [NCHUNK][BN]
    float* Sp    = Up  + NCHUNK * BN;       // [NCHUNK][BM]
    float* Tp    = Sp  + NCHUNK * BM;       // [NCHUNK][BM]  total ~19 MB

    init_kernel<<<dim3(BN / 256), dim3(256), 0, stream>>>(
        xyz1, xyz2, P1, P2, remR, out);

    // levels: j = 7..-1 -> -(4^j), then 0.  coef = level * log2(e)
    float coef[10];
    const double lv[10] = {-16384.0, -4096.0, -1024.0, -256.0, -64.0,
                           -16.0, -4.0, -1.0, -0.25, 0.0};
    for (int i = 0; i < 10; ++i) coef[i] = (float)(lv[i] * 1.4426950408889634);

    dim3 grid(BB * 4 * (NN / CH));          // 16*4*32 = 2048
    dim3 fgrid(BM / 256);                   // 128
    dim3 blk(256);

    rowInit<<<grid, blk, 0, stream>>>(P1, P2, RSp, coef[0]);

    for (int j = 0; j < 10; ++j) {
        const int p = j & 1, q = 1 - p;
        if (j == 0)
            colK<0, true><<<grid, blk, 0, stream>>>(P1, P2, RSp, Up,
                remL + p*BN, remL + q*BN, scale + p*BN, scale + q*BN,
                Sp, Tp, coef[0]);
        else if (j <= 3)
            colK<1, true><<<grid, blk, 0, stream>>>(P1, P2, RSp, Up,
                remL + p*BN, remL + q*BN, scale + p*BN, scale + q*BN,
                Sp, Tp, coef[j]);
        else if (j == 9)
            colK<2, false><<<grid, blk, 0, stream>>>(P1, P2, RSp, Up,
                remL + p*BN, remL + q*BN, scale + p*BN, scale + q*BN,
                Sp, Tp, coef[9]);
        else
            colK<1, false><<<grid, blk, 0, stream>>>(P1, P2, RSp, Up,
                remL + p*BN, remL + q*BN, scale + p*BN, scale + q*BN,
                Sp, Tp, coef[j]);

        if (j < 9) {
            if (j <= 2)
                rowK<1, true><<<grid, blk, 0, stream>>>(P1, P2, Sp, Tp,
                    remR + p*BM, remR + q*BM, RSp, Up, out, coef[j], coef[j+1]);
            else if (j < 8)
                rowK<1, false><<<grid, blk, 0, stream>>>(P1, P2, Sp, Tp,
                    remR + p*BM, remR + q*BM, RSp, Up, out, coef[j], coef[j+1]);
            else
                rowK<2, false><<<grid, blk, 0, stream>>>(P1, P2, Sp, Tp,
                    remR + p*BM, remR + q*BM, RSp, Up, out, coef[8], 0.0f);
        }
    }
    // level 9 cost: partials from colK<2>, remR parity 1 (written by rowK j=8)
    finCost<<<fgrid, blk, 0, stream>>>(Sp, Tp, remR + 1*BM, out);
}